// Round 8
// baseline (222.212 us; speedup 1.0000x reference)
//
#include <hip/hip_runtime.h>
#include <hip/hip_bf16.h>

#define D 512
#define NWAY 64
#define KSHOT 16
#define NQ 8192

typedef __bf16 bf16_t;
typedef __bf16 bf16x8_t __attribute__((ext_vector_type(8)));
typedef float  f32x4    __attribute__((ext_vector_type(4)));

typedef __attribute__((address_space(1))) const void gv_t;
typedef __attribute__((address_space(3))) void lv_t;
__device__ __forceinline__ void ld16(const void* g, void* l) {
    __builtin_amdgcn_global_load_lds((gv_t*)g, (lv_t*)l, 16, 0, 0);
}

// Bsw: [ck(8)][n(576)][seg(8)] bf16, off = ck*36864 + n*64 + ((s^(n&7))*8)
//   rows 0..511 = W (bf16), rows 512..575 = G_c = W^T p_c

// ---------------------------------------------------------------- K_PREP (fused)
// blocks 0..255:  P[c][jq*128..+128] = cm_c . W_j + b_j ; release cnt[c]
// blocks 256..383: W -> bf16 swizzled (independent)
// blocks 384..639: spin on cnt[c]==4, then G_c chunk -> Bsw rows 512+c; kc==0: ph_c
__global__ __launch_bounds__(256) void k_prep(
    const float* __restrict__ sup, const float* __restrict__ W,
    const float* __restrict__ bias, float* __restrict__ Pg,
    bf16_t* __restrict__ Bsw, float* __restrict__ ph, int* __restrict__ cnt)
{
    const int b = blockIdx.x, t = threadIdx.x;

    if (b < 256) {                         // ---- P producer blocks
        const int c = b >> 2, jq = b & 3;
        __shared__ __align__(16) float cm[D];
        {   // cm_c = mean over shots
            const int d = t * 2;
            float sx = 0.f, sy = 0.f;
#pragma unroll
            for (int j = 0; j < KSHOT; ++j) {
                float2 v = *(const float2*)(sup + (size_t)(c * KSHOT + j) * D + d);
                sx += v.x; sy += v.y;
            }
            cm[d] = sx * (1.0f / KSHOT); cm[d + 1] = sy * (1.0f / KSHOT);
        }
        __syncthreads();
        // 128 j per block, each j split over 2 lanes
        const int j = jq * 128 + (t >> 1);
        const int half = t & 1;
        const f32x4* wr = (const f32x4*)(W + (size_t)j * D + half * 256);
        const f32x4* cr = (const f32x4*)(cm + half * 256);
        float s = 0.f;
#pragma unroll 8
        for (int i = 0; i < 64; ++i) {
            f32x4 a = cr[i], wv = wr[i];
            s += a[0]*wv[0] + a[1]*wv[1] + a[2]*wv[2] + a[3]*wv[3];
        }
        s += __shfl_xor(s, 1);
        if (!half) Pg[(size_t)c * D + j] = s + bias[j];
        __threadfence();                   // device-scope visibility of Pg
        __syncthreads();
        if (t == 0)
            __hip_atomic_fetch_add(&cnt[c], 1, __ATOMIC_RELEASE, __HIP_MEMORY_SCOPE_AGENT);
        return;
    }

    if (b < 384) {                         // ---- W conversion, 4 rows/block
        const int n = (b - 256) * 4 + (t >> 6);
        const int sl = t & 63;
        const f32x4* wp = (const f32x4*)(W + (size_t)n * D + sl * 8);
        f32x4 v0 = wp[0], v1 = wp[1];
        bf16x8_t hv = { (bf16_t)v0[0], (bf16_t)v0[1], (bf16_t)v0[2], (bf16_t)v0[3],
                        (bf16_t)v1[0], (bf16_t)v1[1], (bf16_t)v1[2], (bf16_t)v1[3] };
        const int ck = sl >> 3, s = sl & 7;
        *(bf16x8_t*)(Bsw + (size_t)ck * 36864 + n * 64 + ((s ^ (n & 7)) * 8)) = hv;
        return;
    }

    // ---- G consumer blocks
    const int c = (b - 384) >> 2, kc = (b - 384) & 3;
    __shared__ __align__(16) float Pl[D];
    __shared__ float sG[2][128];
    __shared__ float red[4];

    while (__hip_atomic_load(&cnt[c], __ATOMIC_ACQUIRE, __HIP_MEMORY_SCOPE_AGENT) < 4)
        __builtin_amdgcn_s_sleep(8);

    const int kl = t & 127, jh = t >> 7;
    const int k = kc * 128 + kl;

    ((float2*)Pl)[t] = ((const float2*)(Pg + (size_t)c * D))[t];
    __syncthreads();

    float g = 0.f;
    const float* wcol = W + (size_t)jh * 256 * D + k;
#pragma unroll 8
    for (int j = 0; j < 256; ++j)
        g += Pl[jh * 256 + j] * wcol[(size_t)j * D];
    sG[jh][kl] = g;

    if (kc == 0) {
        float v1 = Pl[t], v2 = Pl[t + 256];
        float pp = v1 * v1 - 2.0f * bias[t] * v1 + v2 * v2 - 2.0f * bias[t + 256] * v2;
#pragma unroll
        for (int off = 32; off; off >>= 1) pp += __shfl_xor(pp, off);
        if ((t & 63) == 0) red[t >> 6] = pp;
    }
    __syncthreads();

    if (jh == 0) {
        const float gt = sG[0][kl] + sG[1][kl];
        const int n = 512 + c;
        const int ckk = k >> 6, s = (k >> 3) & 7, e = k & 7;
        Bsw[(size_t)ckk * 36864 + n * 64 + ((s ^ (c & 7)) * 8) + e] = (bf16_t)gt;
    }
    if (kc == 0 && t == 0) ph[c] = red[0] + red[1] + red[2] + red[3];
}

// ---------------------------------------------------------------- K_MAIN
// 256 blocks x 512 thr, 2 blocks/CU. Per chunk: issue B-DMA first, store A
// from prefetched regs (no global dep), barrier, issue next A loads, MFMA
// covers their latency. Conflict-free XOR-swizzled frag reads; qn in regs.
__global__ __launch_bounds__(512, 2) void k_main(
    const float* __restrict__ query, const bf16_t* __restrict__ Bsw,
    const float* __restrict__ bias, const float* __restrict__ ph,
    float* __restrict__ out)
{
    __shared__ bf16_t Bb[36864];   // 73,728 B
    __shared__ bf16_t Ab[2048];    //  4,096 B
    __shared__ float qln[4][32];
    __shared__ float phs[NWAY];
    __shared__ float bs[576];      // total 80,896 B -> 2 blocks/CU

    const int t = threadIdx.x, bm = blockIdx.x;
    if (t < 512) bs[t] = bias[t];
    if (t < NWAY) { bs[512 + t] = 0.f; phs[t] = ph[t]; }

    const int l = t & 63, w = t >> 6;
    const int wm = w & 1, wn = w >> 1;
    const int r15 = l & 15, quad = l >> 4;

    const int xt0 = ((quad ^ (r15 & 7)) * 8);
    const int xt1 = (((4 + quad) ^ (r15 & 7)) * 8);
    const int aoff = (wm * 16 + r15) * 64;
    const int boff = (wn * 144 + r15) * 64;

    // A-staging coords (waves 0..3: 32 rows x 8 segs)
    const int am = (w * 64 + l) >> 3;
    const int as = l & 7;
    const float* aq = query + (size_t)(bm * 32 + am) * D + as * 8;
    bf16_t* adst = Ab + am * 64 + ((as ^ (am & 7)) * 8);

    f32x4 acc[9];
#pragma unroll
    for (int i = 0; i < 9; ++i) acc[i] = (f32x4){0.f, 0.f, 0.f, 0.f};

    f32x4 a0, a1;                          // A prefetch registers
    if (w < 4) { a0 = *(const f32x4*)(aq); a1 = *(const f32x4*)(aq + 4); }

    for (int ck = 0; ck < 8; ++ck) {
        if (ck) __syncthreads();           // WAR guard on LDS reuse
        {                                  // 1) issue async B-DMA first
            const int wb = w * 4608 + l * 8;
#pragma unroll
            for (int i = 0; i < 9; ++i) {
                const int off = wb + i * 512;
                ld16(Bsw + (size_t)ck * 36864 + off, Bb + off);
            }
        }
        if (w < 4) {                       // 2) store A chunk from prefetched regs
            bf16x8_t hv = { (bf16_t)a0[0], (bf16_t)a0[1], (bf16_t)a0[2], (bf16_t)a0[3],
                            (bf16_t)a1[0], (bf16_t)a1[1], (bf16_t)a1[2], (bf16_t)a1[3] };
            *(bf16x8_t*)adst = hv;
        }
        __syncthreads();                   // drains B-DMA
        if (w < 4 && ck < 7) {             // 3) issue next A loads; MFMA covers them
            a0 = *(const f32x4*)(aq + (ck + 1) * 64);
            a1 = *(const f32x4*)(aq + (ck + 1) * 64 + 4);
        }

        bf16x8_t fa0 = *(const bf16x8_t*)(Ab + aoff + xt0);
        bf16x8_t fa1 = *(const bf16x8_t*)(Ab + aoff + xt1);
#pragma unroll
        for (int tt = 0; tt < 9; ++tt) {
            bf16x8_t b0 = *(const bf16x8_t*)(Bb + boff + tt * 1024 + xt0);
            bf16x8_t b1 = *(const bf16x8_t*)(Bb + boff + tt * 1024 + xt1);
            acc[tt] = __builtin_amdgcn_mfma_f32_16x16x32_bf16(fa0, b0, acc[tt], 0, 0, 0);
            acc[tt] = __builtin_amdgcn_mfma_f32_16x16x32_bf16(fa1, b1, acc[tt], 0, 0, 0);
        }
    }

    // ---- qn = sum over W-cols of (e + bias)^2 ; constant bound, masked ----
    float qp[4] = {0.f, 0.f, 0.f, 0.f};
#pragma unroll
    for (int tt = 0; tt < 9; ++tt) {
        const int colbase = wn * 144 + tt * 16;
        const float m = (colbase < 512) ? 1.f : 0.f;   // wave-uniform
        const float bv = bs[colbase + r15];
#pragma unroll
        for (int reg = 0; reg < 4; ++reg) {
            float v = acc[tt][reg] + bv;
            qp[reg] += m * v * v;
        }
    }
#pragma unroll
    for (int reg = 0; reg < 4; ++reg) {
        float s = qp[reg];
        s += __shfl_xor(s, 1); s += __shfl_xor(s, 2);
        s += __shfl_xor(s, 4); s += __shfl_xor(s, 8);
        if (r15 == 0) qln[wn][wm * 16 + quad * 4 + reg] = s;
    }
    __syncthreads();

    // ---- wn==3 waves write dists: qt + ph[c] - 2 * (q.G_c) ----
    if (wn == 3) {
#pragma unroll
        for (int reg = 0; reg < 4; ++reg) {
            const int row_local = quad * 4 + reg;
            const float qt = qln[0][wm * 16 + row_local] + qln[1][wm * 16 + row_local] +
                             qln[2][wm * 16 + row_local] + qln[3][wm * 16 + row_local];
            const int rowg = bm * 32 + wm * 16 + row_local;
#pragma unroll
            for (int tg = 0; tg < 4; ++tg) {
                const int c = tg * 16 + r15;
                out[(size_t)rowg * NWAY + c] = qt + phs[c] - 2.0f * acc[5 + tg][reg];
            }
        }
    }
}

// ---------------------------------------------------------------- launch
extern "C" void kernel_launch(void* const* d_in, const int* in_sizes, int n_in,
                              void* d_out, int out_size, void* d_ws, size_t ws_size,
                              hipStream_t stream)
{
    const float* support = (const float*)d_in[0];
    const float* query   = (const float*)d_in[1];
    const float* W       = (const float*)d_in[2];
    const float* bias    = (const float*)d_in[3];
    float* out = (float*)d_out;

    char* ws = (char*)d_ws;
    bf16_t* Bsw = (bf16_t*)ws;                          // 589,824 B
    float*  ph  = (float*)(ws + 589824);                //     256 B
    float*  Pg  = (float*)(ws + 589824 + 256);          // 131,072 B
    int*    cnt = (int*)(ws + 589824 + 256 + 131072);   //     256 B

    hipMemsetAsync(cnt, 0, NWAY * sizeof(int), stream);
    k_prep<<<640, 256, 0, stream>>>(support, W, bias, Pg, Bsw, ph, cnt);
    k_main<<<256, 512, 0, stream>>>(query, Bsw, bias, ph, out);
}

// Round 10
// 157.736 us; speedup vs baseline: 1.4088x; 1.4088x over previous
//
#include <hip/hip_runtime.h>
#include <hip/hip_bf16.h>

#define D 512
#define NWAY 64
#define KSHOT 16
#define NQ 8192
#define SENT 0x5EED5EED

typedef __bf16 bf16_t;
typedef __bf16 bf16x8_t __attribute__((ext_vector_type(8)));
typedef float  f32x4    __attribute__((ext_vector_type(4)));

typedef __attribute__((address_space(1))) const void gv_t;
typedef __attribute__((address_space(3))) void lv_t;
__device__ __forceinline__ void ld16(const void* g, void* l) {
    __builtin_amdgcn_global_load_lds((gv_t*)g, (lv_t*)l, 16, 0, 0);
}

// Bsw: [ck(8)][n(576)][seg(8)] bf16, off = ck*36864 + n*64 + ((s^(n&7))*8)
//   rows 0..511 = W (bf16), rows 512..575 = G_c = W^T p_c

// ---------------------------------------------------------------- K_PREP (fused)
// blocks 0..255:  P[c][jq*128..+128] = cm_c . W_j + b_j ; release done[b] = SENT
// blocks 256..383: W -> bf16 swizzled (independent)
// blocks 384..639: lane-0 spin on done[c*4..+4]==SENT, then G_c chunk; kc==0: ph_c
__global__ __launch_bounds__(256) void k_prep(
    const float* __restrict__ sup, const float* __restrict__ W,
    const float* __restrict__ bias, float* __restrict__ Pg,
    bf16_t* __restrict__ Bsw, float* __restrict__ ph, int* __restrict__ done)
{
    const int b = blockIdx.x, t = threadIdx.x;

    if (b < 256) {                         // ---- P producer blocks
        const int c = b >> 2, jq = b & 3;
        __shared__ __align__(16) float cm[D];
        {   // cm_c = mean over shots
            const int d = t * 2;
            float sx = 0.f, sy = 0.f;
#pragma unroll
            for (int j = 0; j < KSHOT; ++j) {
                float2 v = *(const float2*)(sup + (size_t)(c * KSHOT + j) * D + d);
                sx += v.x; sy += v.y;
            }
            cm[d] = sx * (1.0f / KSHOT); cm[d + 1] = sy * (1.0f / KSHOT);
        }
        __syncthreads();
        const int j = jq * 128 + (t >> 1);
        const int half = t & 1;
        const f32x4* wr = (const f32x4*)(W + (size_t)j * D + half * 256);
        const f32x4* cr = (const f32x4*)(cm + half * 256);
        float s = 0.f;
#pragma unroll 8
        for (int i = 0; i < 64; ++i) {
            f32x4 a = cr[i], wv = wr[i];
            s += a[0]*wv[0] + a[1]*wv[1] + a[2]*wv[2] + a[3]*wv[3];
        }
        s += __shfl_xor(s, 1);
        if (!half) Pg[(size_t)c * D + j] = s + bias[j];
        __threadfence();                   // make Pg visible device-wide
        __syncthreads();
        if (t == 0)
            __hip_atomic_store(&done[b], SENT, __ATOMIC_RELEASE, __HIP_MEMORY_SCOPE_AGENT);
        return;
    }

    if (b < 384) {                         // ---- W conversion, 4 rows/block
        const int n = (b - 256) * 4 + (t >> 6);
        const int sl = t & 63;
        const f32x4* wp = (const f32x4*)(W + (size_t)n * D + sl * 8);
        f32x4 v0 = wp[0], v1 = wp[1];
        bf16x8_t hv = { (bf16_t)v0[0], (bf16_t)v0[1], (bf16_t)v0[2], (bf16_t)v0[3],
                        (bf16_t)v1[0], (bf16_t)v1[1], (bf16_t)v1[2], (bf16_t)v1[3] };
        const int ck = sl >> 3, s = sl & 7;
        *(bf16x8_t*)(Bsw + (size_t)ck * 36864 + n * 64 + ((s ^ (n & 7)) * 8)) = hv;
        return;
    }

    // ---- G consumer blocks
    const int c = (b - 384) >> 2, kc = (b - 384) & 3;
    __shared__ __align__(16) float Pl[D];
    __shared__ float sG[2][128];
    __shared__ float red[4];

    if (t == 0) {                          // single-lane spin (G12: no atomic storm)
#pragma unroll
        for (int i = 0; i < 4; ++i)
            while (__hip_atomic_load(&done[c * 4 + i], __ATOMIC_ACQUIRE,
                                     __HIP_MEMORY_SCOPE_AGENT) != SENT)
                __builtin_amdgcn_s_sleep(16);
    }
    __syncthreads();
    __builtin_amdgcn_fence(__ATOMIC_ACQUIRE, "agent");

    const int kl = t & 127, jh = t >> 7;
    const int k = kc * 128 + kl;

    ((float2*)Pl)[t] = ((const float2*)(Pg + (size_t)c * D))[t];
    __syncthreads();

    float g = 0.f;
    const float* wcol = W + (size_t)jh * 256 * D + k;
#pragma unroll 8
    for (int j = 0; j < 256; ++j)
        g += Pl[jh * 256 + j] * wcol[(size_t)j * D];
    sG[jh][kl] = g;

    if (kc == 0) {
        float v1 = Pl[t], v2 = Pl[t + 256];
        float pp = v1 * v1 - 2.0f * bias[t] * v1 + v2 * v2 - 2.0f * bias[t + 256] * v2;
#pragma unroll
        for (int off = 32; off; off >>= 1) pp += __shfl_xor(pp, off);
        if ((t & 63) == 0) red[t >> 6] = pp;
    }
    __syncthreads();

    if (jh == 0) {
        const float gt = sG[0][kl] + sG[1][kl];
        const int n = 512 + c;
        const int ckk = k >> 6, s = (k >> 3) & 7, e = k & 7;
        Bsw[(size_t)ckk * 36864 + n * 64 + ((s ^ (c & 7)) * 8) + e] = (bf16_t)gt;
    }
    if (kc == 0 && t == 0) ph[c] = red[0] + red[1] + red[2] + red[3];
}

// ---------------------------------------------------------------- K_MAIN
// 256 blocks x 512 thr, 1 block/CU, DOUBLE-BUFFERED LDS (155.6 KB):
// per chunk: DMA(ck+1) -> other buffer, MFMA(ck), barrier. The vmcnt(0)
// drain at the barrier lands after the MFMA stretch -> DMA latency hidden.
__global__ __launch_bounds__(512, 1) void k_main(
    const float* __restrict__ query, const bf16_t* __restrict__ Bsw,
    const float* __restrict__ bias, const float* __restrict__ ph,
    float* __restrict__ out)
{
    __shared__ bf16_t Bb[2][36864];   // 147,456 B
    __shared__ bf16_t Ab[2][2048];    //   8,192 B
    __shared__ float qln[4][32];
    __shared__ float phs[NWAY];
    __shared__ float bs[576];

    const int t = threadIdx.x, bm = blockIdx.x;
    if (t < 512) bs[t] = bias[t];
    if (t < NWAY) { bs[512 + t] = 0.f; phs[t] = ph[t]; }

    const int l = t & 63, w = t >> 6;
    const int wm = w & 1, wn = w >> 1;
    const int r15 = l & 15, quad = l >> 4;

    const int xt0 = ((quad ^ (r15 & 7)) * 8);
    const int xt1 = (((4 + quad) ^ (r15 & 7)) * 8);
    const int aoff = (wm * 16 + r15) * 64;
    const int boff = (wn * 144 + r15) * 64;
    const int wb   = w * 4608 + l * 8;

    // A-staging coords (waves 0..3: 32 rows x 8 segs)
    const int am = (w * 64 + l) >> 3;
    const int as = l & 7;
    const float* aq = query + (size_t)(bm * 32 + am) * D + as * 8;
    const int adst = am * 64 + ((as ^ (am & 7)) * 8);

    f32x4 acc[9];
#pragma unroll
    for (int i = 0; i < 9; ++i) acc[i] = (f32x4){0.f, 0.f, 0.f, 0.f};

    f32x4 a0, a1;                          // A prefetch registers
    // ---- prologue: chunk 0 into buffer 0; prefetch A regs for chunk 1 ----
    if (w < 4) {
        f32x4 p0 = *(const f32x4*)(aq), p1 = *(const f32x4*)(aq + 4);
        bf16x8_t hv = { (bf16_t)p0[0], (bf16_t)p0[1], (bf16_t)p0[2], (bf16_t)p0[3],
                        (bf16_t)p1[0], (bf16_t)p1[1], (bf16_t)p1[2], (bf16_t)p1[3] };
        *(bf16x8_t*)(Ab[0] + adst) = hv;
        a0 = *(const f32x4*)(aq + 64);
        a1 = *(const f32x4*)(aq + 64 + 4);
    }
#pragma unroll
    for (int i = 0; i < 9; ++i) {
        const int off = wb + i * 512;
        ld16(Bsw + off, Bb[0] + off);
    }
    __syncthreads();

    for (int ck = 0; ck < 8; ++ck) {
        const int cb = ck & 1, nb = cb ^ 1;
        if (ck < 7) {
            if (w < 4) {                   // store A(ck+1) from prefetched regs
                bf16x8_t hv = { (bf16_t)a0[0], (bf16_t)a0[1], (bf16_t)a0[2], (bf16_t)a0[3],
                                (bf16_t)a1[0], (bf16_t)a1[1], (bf16_t)a1[2], (bf16_t)a1[3] };
                *(bf16x8_t*)(Ab[nb] + adst) = hv;
            }
#pragma unroll
            for (int i = 0; i < 9; ++i) {  // async DMA B(ck+1) into other buffer
                const int off = wb + i * 512;
                ld16(Bsw + (size_t)(ck + 1) * 36864 + off, Bb[nb] + off);
            }
            if (w < 4 && ck < 6) {         // prefetch A regs for chunk ck+2
                a0 = *(const f32x4*)(aq + (ck + 2) * 64);
                a1 = *(const f32x4*)(aq + (ck + 2) * 64 + 4);
            }
        }

        bf16x8_t fa0 = *(const bf16x8_t*)(Ab[cb] + aoff + xt0);
        bf16x8_t fa1 = *(const bf16x8_t*)(Ab[cb] + aoff + xt1);
#pragma unroll
        for (int tt = 0; tt < 9; ++tt) {
            bf16x8_t b0 = *(const bf16x8_t*)(Bb[cb] + boff + tt * 1024 + xt0);
            bf16x8_t b1 = *(const bf16x8_t*)(Bb[cb] + boff + tt * 1024 + xt1);
            acc[tt] = __builtin_amdgcn_mfma_f32_16x16x32_bf16(fa0, b0, acc[tt], 0, 0, 0);
            acc[tt] = __builtin_amdgcn_mfma_f32_16x16x32_bf16(fa1, b1, acc[tt], 0, 0, 0);
        }
        __syncthreads();                   // drains DMA(ck+1); releases buf cb
    }

    // ---- qn = sum over W-cols of (e + bias)^2 ; constant bound, masked ----
    float qp[4] = {0.f, 0.f, 0.f, 0.f};
#pragma unroll
    for (int tt = 0; tt < 9; ++tt) {
        const int colbase = wn * 144 + tt * 16;
        const float m = (colbase < 512) ? 1.f : 0.f;   // wave-uniform
        const float bv = bs[colbase + r15];
#pragma unroll
        for (int reg = 0; reg < 4; ++reg) {
            float v = acc[tt][reg] + bv;
            qp[reg] += m * v * v;
        }
    }
#pragma unroll
    for (int reg = 0; reg < 4; ++reg) {
        float s = qp[reg];
        s += __shfl_xor(s, 1); s += __shfl_xor(s, 2);
        s += __shfl_xor(s, 4); s += __shfl_xor(s, 8);
        if (r15 == 0) qln[wn][wm * 16 + quad * 4 + reg] = s;
    }
    __syncthreads();

    // ---- wn==3 waves write dists: qt + ph[c] - 2 * (q.G_c) ----
    if (wn == 3) {
#pragma unroll
        for (int reg = 0; reg < 4; ++reg) {
            const int row_local = quad * 4 + reg;
            const float qt = qln[0][wm * 16 + row_local] + qln[1][wm * 16 + row_local] +
                             qln[2][wm * 16 + row_local] + qln[3][wm * 16 + row_local];
            const int rowg = bm * 32 + wm * 16 + row_local;
#pragma unroll
            for (int tg = 0; tg < 4; ++tg) {
                const int c = tg * 16 + r15;
                out[(size_t)rowg * NWAY + c] = qt + phs[c] - 2.0f * acc[5 + tg][reg];
            }
        }
    }
}

// ---------------------------------------------------------------- launch
extern "C" void kernel_launch(void* const* d_in, const int* in_sizes, int n_in,
                              void* d_out, int out_size, void* d_ws, size_t ws_size,
                              hipStream_t stream)
{
    const float* support = (const float*)d_in[0];
    const float* query   = (const float*)d_in[1];
    const float* W       = (const float*)d_in[2];
    const float* bias    = (const float*)d_in[3];
    float* out = (float*)d_out;

    char* ws = (char*)d_ws;
    bf16_t* Bsw  = (bf16_t*)ws;                          // 589,824 B
    float*  ph   = (float*)(ws + 589824);                //     256 B
    float*  Pg   = (float*)(ws + 589824 + 256);          // 131,072 B
    int*    done = (int*)(ws + 589824 + 256 + 131072);   //   1,024 B

    k_prep<<<640, 256, 0, stream>>>(support, W, bias, Pg, Bsw, ph, done);
    k_main<<<256, 512, 0, stream>>>(query, Bsw, bias, ph, out);
}

// Round 11
// 124.251 us; speedup vs baseline: 1.7884x; 1.2695x over previous
//
#include <hip/hip_runtime.h>
#include <hip/hip_bf16.h>

#define D 512
#define NWAY 64
#define KSHOT 16
#define NQ 8192

typedef __bf16 bf16_t;
typedef __bf16 bf16x8_t __attribute__((ext_vector_type(8)));
typedef float  f32x4    __attribute__((ext_vector_type(4)));

typedef __attribute__((address_space(1))) const void gv_t;
typedef __attribute__((address_space(3))) void lv_t;
__device__ __forceinline__ void ld16(const void* g, void* l) {
    __builtin_amdgcn_global_load_lds((gv_t*)g, (lv_t*)l, 16, 0, 0);
}

// Bsw: [ck(8)][n(576)][seg(8)] bf16, off = ck*36864 + n*64 + ((s^(n&7))*8)
//   rows 0..511 = W (bf16), rows 512..575 = G_c = W^T p_c

// ---------------------------------------------------------------- K_PREP
// NO cross-block dependencies (G16: per-XCD L2 non-coherence burned us twice).
// blocks 0..255 (c = b>>2, kq = b&3): recompute cm_c AND full P_c locally,
//   then G_c[kq*128..+128] -> Bsw; kq==0 also writes ph_c.
// blocks 256..383: W -> bf16 swizzled.
__global__ __launch_bounds__(256) void k_prep(
    const float* __restrict__ sup, const float* __restrict__ W,
    const float* __restrict__ bias, bf16_t* __restrict__ Bsw,
    float* __restrict__ ph)
{
    const int b = blockIdx.x, t = threadIdx.x;

    if (b >= 256) {                        // ---- W conversion, 4 rows/block
        const int n = (b - 256) * 4 + (t >> 6);
        const int sl = t & 63;
        const f32x4* wp = (const f32x4*)(W + (size_t)n * D + sl * 8);
        f32x4 v0 = wp[0], v1 = wp[1];
        bf16x8_t hv = { (bf16_t)v0[0], (bf16_t)v0[1], (bf16_t)v0[2], (bf16_t)v0[3],
                        (bf16_t)v1[0], (bf16_t)v1[1], (bf16_t)v1[2], (bf16_t)v1[3] };
        const int ck = sl >> 3, s = sl & 7;
        *(bf16x8_t*)(Bsw + (size_t)ck * 36864 + n * 64 + ((s ^ (n & 7)) * 8)) = hv;
        return;
    }

    // ---- fused class chain, fully block-local
    const int c = b >> 2, kq = b & 3;
    __shared__ __align__(16) float cm[D];
    __shared__ __align__(16) float Pl[D];
    __shared__ float sG[2][128];
    __shared__ float red[4];

    {   // 1) cm_c = mean over shots
        const int d = t * 2;
        float sx = 0.f, sy = 0.f;
#pragma unroll
        for (int j = 0; j < KSHOT; ++j) {
            float2 v = *(const float2*)(sup + (size_t)(c * KSHOT + j) * D + d);
            sx += v.x; sy += v.y;
        }
        cm[d] = sx * (1.0f / KSHOT); cm[d + 1] = sy * (1.0f / KSHOT);
    }
    __syncthreads();

    {   // 2) full P_c in LDS: thread t computes j = t and j = t+256
#pragma unroll
        for (int h = 0; h < 2; ++h) {
            const int j = t + h * 256;
            const f32x4* wr = (const f32x4*)(W + (size_t)j * D);
            const f32x4* cr = (const f32x4*)cm;
            float s = 0.f;
#pragma unroll 8
            for (int i = 0; i < 128; ++i) {
                f32x4 a = cr[i], wv = wr[i];
                s += a[0]*wv[0] + a[1]*wv[1] + a[2]*wv[2] + a[3]*wv[3];
            }
            Pl[j] = s + bias[j];
        }
    }
    __syncthreads();

    {   // 3) G chunk: k in [kq*128, +128), j split x2 across thread halves
        const int kl = t & 127, jh = t >> 7;
        const int k = kq * 128 + kl;
        float g = 0.f;
        const float* wcol = W + (size_t)jh * 256 * D + k;
#pragma unroll 8
        for (int j = 0; j < 256; ++j)
            g += Pl[jh * 256 + j] * wcol[(size_t)j * D];
        sG[jh][kl] = g;

        if (kq == 0) {                     // 4) ph_c = ||p||^2 - 2 b.p
            float v1 = Pl[t], v2 = Pl[t + 256];
            float pp = v1 * v1 - 2.0f * bias[t] * v1 + v2 * v2 - 2.0f * bias[t + 256] * v2;
#pragma unroll
            for (int off = 32; off; off >>= 1) pp += __shfl_xor(pp, off);
            if ((t & 63) == 0) red[t >> 6] = pp;
        }
        __syncthreads();

        if (jh == 0) {
            const float gt = sG[0][kl] + sG[1][kl];
            const int n = 512 + c;
            const int ckk = k >> 6, s = (k >> 3) & 7, e = k & 7;
            Bsw[(size_t)ckk * 36864 + n * 64 + ((s ^ (c & 7)) * 8) + e] = (bf16_t)gt;
        }
        if (kq == 0 && t == 0) ph[c] = red[0] + red[1] + red[2] + red[3];
    }
}

// ---------------------------------------------------------------- K_MAIN
// 256 blocks x 512 thr, 1 block/CU, DOUBLE-BUFFERED LDS: per chunk issue
// DMA(ck+1) into other buffer, MFMA(ck), barrier (drains DMA after MFMA).
__global__ __launch_bounds__(512, 1) void k_main(
    const float* __restrict__ query, const bf16_t* __restrict__ Bsw,
    const float* __restrict__ bias, const float* __restrict__ ph,
    float* __restrict__ out)
{
    __shared__ bf16_t Bb[2][36864];   // 147,456 B
    __shared__ bf16_t Ab[2][2048];    //   8,192 B
    __shared__ float qln[4][32];
    __shared__ float phs[NWAY];
    __shared__ float bs[576];

    const int t = threadIdx.x, bm = blockIdx.x;
    if (t < 512) bs[t] = bias[t];
    if (t < NWAY) { bs[512 + t] = 0.f; phs[t] = ph[t]; }

    const int l = t & 63, w = t >> 6;
    const int wm = w & 1, wn = w >> 1;
    const int r15 = l & 15, quad = l >> 4;

    const int xt0 = ((quad ^ (r15 & 7)) * 8);
    const int xt1 = (((4 + quad) ^ (r15 & 7)) * 8);
    const int aoff = (wm * 16 + r15) * 64;
    const int boff = (wn * 144 + r15) * 64;
    const int wb   = w * 4608 + l * 8;

    const int am = (w * 64 + l) >> 3;
    const int as = l & 7;
    const float* aq = query + (size_t)(bm * 32 + am) * D + as * 8;
    const int adst = am * 64 + ((as ^ (am & 7)) * 8);

    f32x4 acc[9];
#pragma unroll
    for (int i = 0; i < 9; ++i) acc[i] = (f32x4){0.f, 0.f, 0.f, 0.f};

    f32x4 a0, a1;
    if (w < 4) {
        f32x4 p0 = *(const f32x4*)(aq), p1 = *(const f32x4*)(aq + 4);
        bf16x8_t hv = { (bf16_t)p0[0], (bf16_t)p0[1], (bf16_t)p0[2], (bf16_t)p0[3],
                        (bf16_t)p1[0], (bf16_t)p1[1], (bf16_t)p1[2], (bf16_t)p1[3] };
        *(bf16x8_t*)(Ab[0] + adst) = hv;
        a0 = *(const f32x4*)(aq + 64);
        a1 = *(const f32x4*)(aq + 64 + 4);
    }
#pragma unroll
    for (int i = 0; i < 9; ++i) {
        const int off = wb + i * 512;
        ld16(Bsw + off, Bb[0] + off);
    }
    __syncthreads();

    for (int ck = 0; ck < 8; ++ck) {
        const int cb = ck & 1, nb = cb ^ 1;
        if (ck < 7) {
            if (w < 4) {
                bf16x8_t hv = { (bf16_t)a0[0], (bf16_t)a0[1], (bf16_t)a0[2], (bf16_t)a0[3],
                                (bf16_t)a1[0], (bf16_t)a1[1], (bf16_t)a1[2], (bf16_t)a1[3] };
                *(bf16x8_t*)(Ab[nb] + adst) = hv;
            }
#pragma unroll
            for (int i = 0; i < 9; ++i) {
                const int off = wb + i * 512;
                ld16(Bsw + (size_t)(ck + 1) * 36864 + off, Bb[nb] + off);
            }
            if (w < 4 && ck < 6) {
                a0 = *(const f32x4*)(aq + (ck + 2) * 64);
                a1 = *(const f32x4*)(aq + (ck + 2) * 64 + 4);
            }
        }

        bf16x8_t fa0 = *(const bf16x8_t*)(Ab[cb] + aoff + xt0);
        bf16x8_t fa1 = *(const bf16x8_t*)(Ab[cb] + aoff + xt1);
#pragma unroll
        for (int tt = 0; tt < 9; ++tt) {
            bf16x8_t b0 = *(const bf16x8_t*)(Bb[cb] + boff + tt * 1024 + xt0);
            bf16x8_t b1 = *(const bf16x8_t*)(Bb[cb] + boff + tt * 1024 + xt1);
            acc[tt] = __builtin_amdgcn_mfma_f32_16x16x32_bf16(fa0, b0, acc[tt], 0, 0, 0);
            acc[tt] = __builtin_amdgcn_mfma_f32_16x16x32_bf16(fa1, b1, acc[tt], 0, 0, 0);
        }
        __syncthreads();
    }

    // ---- qn = sum over W-cols of (e + bias)^2 ; constant bound, masked ----
    float qp[4] = {0.f, 0.f, 0.f, 0.f};
#pragma unroll
    for (int tt = 0; tt < 9; ++tt) {
        const int colbase = wn * 144 + tt * 16;
        const float m = (colbase < 512) ? 1.f : 0.f;   // wave-uniform
        const float bv = bs[colbase + r15];
#pragma unroll
        for (int reg = 0; reg < 4; ++reg) {
            float v = acc[tt][reg] + bv;
            qp[reg] += m * v * v;
        }
    }
#pragma unroll
    for (int reg = 0; reg < 4; ++reg) {
        float s = qp[reg];
        s += __shfl_xor(s, 1); s += __shfl_xor(s, 2);
        s += __shfl_xor(s, 4); s += __shfl_xor(s, 8);
        if (r15 == 0) qln[wn][wm * 16 + quad * 4 + reg] = s;
    }
    __syncthreads();

    if (wn == 3) {
#pragma unroll
        for (int reg = 0; reg < 4; ++reg) {
            const int row_local = quad * 4 + reg;
            const float qt = qln[0][wm * 16 + row_local] + qln[1][wm * 16 + row_local] +
                             qln[2][wm * 16 + row_local] + qln[3][wm * 16 + row_local];
            const int rowg = bm * 32 + wm * 16 + row_local;
#pragma unroll
            for (int tg = 0; tg < 4; ++tg) {
                const int c = tg * 16 + r15;
                out[(size_t)rowg * NWAY + c] = qt + phs[c] - 2.0f * acc[5 + tg][reg];
            }
        }
    }
}

// ---------------------------------------------------------------- launch
extern "C" void kernel_launch(void* const* d_in, const int* in_sizes, int n_in,
                              void* d_out, int out_size, void* d_ws, size_t ws_size,
                              hipStream_t stream)
{
    const float* support = (const float*)d_in[0];
    const float* query   = (const float*)d_in[1];
    const float* W       = (const float*)d_in[2];
    const float* bias    = (const float*)d_in[3];
    float* out = (float*)d_out;

    char* ws = (char*)d_ws;
    bf16_t* Bsw = (bf16_t*)ws;                 // 589,824 B
    float*  ph  = (float*)(ws + 589824);       //     256 B

    k_prep<<<384, 256, 0, stream>>>(support, W, bias, Bsw, ph);
    k_main<<<256, 512, 0, stream>>>(query, Bsw, bias, ph, out);
}

// Round 12
// 115.857 us; speedup vs baseline: 1.9180x; 1.0724x over previous
//
#include <hip/hip_runtime.h>
#include <hip/hip_bf16.h>

#define D 512
#define NWAY 64
#define KSHOT 16
#define NQ 8192

typedef __bf16 bf16_t;
typedef __bf16 bf16x8_t __attribute__((ext_vector_type(8)));
typedef float  f32x4    __attribute__((ext_vector_type(4)));

typedef __attribute__((address_space(1))) const void gv_t;
typedef __attribute__((address_space(3))) void lv_t;
__device__ __forceinline__ void ld16(const void* g, void* l) {
    __builtin_amdgcn_global_load_lds((gv_t*)g, (lv_t*)l, 16, 0, 0);
}

// Bsw v2 (16 K-chunks of 32): elem off = ck*18432 + n*32 + ((s ^ (n&3))*8) + e
//   ck = k>>5, s = (k>>3)&3 (seg within chunk), e = k&7.
//   rows 0..511 = W (bf16), rows 512..575 = G_c = W^T p_c

// ---------------------------------------------------------------- K_PREP1
// blocks 0..255: P[c][jq*128..+128] = cm_c . W_j + b_j  (dep-free, R7-proven)
// blocks 256..383: W -> bf16 swizzled into Bsw rows 0..511
__global__ __launch_bounds__(256) void k_prep1(
    const float* __restrict__ sup, const float* __restrict__ W,
    const float* __restrict__ bias, float* __restrict__ Pg,
    bf16_t* __restrict__ Bsw)
{
    const int b = blockIdx.x, t = threadIdx.x;

    if (b < 256) {                         // ---- P blocks
        const int c = b >> 2, jq = b & 3;
        __shared__ __align__(16) float cm[D];
        {   // cm_c = mean over shots
            const int d = t * 2;
            float sx = 0.f, sy = 0.f;
#pragma unroll
            for (int j = 0; j < KSHOT; ++j) {
                float2 v = *(const float2*)(sup + (size_t)(c * KSHOT + j) * D + d);
                sx += v.x; sy += v.y;
            }
            cm[d] = sx * (1.0f / KSHOT); cm[d + 1] = sy * (1.0f / KSHOT);
        }
        __syncthreads();
        const int j = jq * 128 + (t >> 1);
        const int half = t & 1;
        const f32x4* wr = (const f32x4*)(W + (size_t)j * D + half * 256);
        const f32x4* cr = (const f32x4*)(cm + half * 256);
        float s = 0.f;
#pragma unroll 8
        for (int i = 0; i < 64; ++i) {
            f32x4 a = cr[i], wv = wr[i];
            s += a[0]*wv[0] + a[1]*wv[1] + a[2]*wv[2] + a[3]*wv[3];
        }
        s += __shfl_xor(s, 1);
        if (!half) Pg[(size_t)c * D + j] = s + bias[j];
        return;
    }

    {                                      // ---- W conversion, 4 rows/block
        const int n = (b - 256) * 4 + (t >> 6);
        const int sl = t & 63;             // seg 0..63 of the row (8 elems each)
        const f32x4* wp = (const f32x4*)(W + (size_t)n * D + sl * 8);
        f32x4 v0 = wp[0], v1 = wp[1];
        bf16x8_t hv = { (bf16_t)v0[0], (bf16_t)v0[1], (bf16_t)v0[2], (bf16_t)v0[3],
                        (bf16_t)v1[0], (bf16_t)v1[1], (bf16_t)v1[2], (bf16_t)v1[3] };
        const int ck = sl >> 2, s = sl & 3;
        *(bf16x8_t*)(Bsw + (size_t)ck * 18432 + n * 32 + ((s ^ (n & 3)) * 8)) = hv;
    }
}

// ---------------------------------------------------------------- K_PREP2
// 256 blocks: G_c[kc*128..+128] -> Bsw rows 512+c; kc==0 also ph_c.
// Lane-consecutive-k W reads (coalesced); Pg via kernel boundary (dep-free).
__global__ __launch_bounds__(256) void k_prep2(
    const float* __restrict__ Pg, const float* __restrict__ W,
    const float* __restrict__ bias, bf16_t* __restrict__ Bsw,
    float* __restrict__ ph)
{
    __shared__ __align__(16) float Pl[D];
    __shared__ float sG[2][128];
    __shared__ float red[4];

    const int c = blockIdx.x >> 2, kc = blockIdx.x & 3;
    const int t = threadIdx.x;
    const int kl = t & 127, jh = t >> 7;
    const int k = kc * 128 + kl;

    ((float2*)Pl)[t] = ((const float2*)(Pg + (size_t)c * D))[t];
    __syncthreads();

    float g = 0.f;
    const float* wcol = W + (size_t)jh * 256 * D + k;
#pragma unroll 8
    for (int j = 0; j < 256; ++j)
        g += Pl[jh * 256 + j] * wcol[(size_t)j * D];
    sG[jh][kl] = g;

    if (kc == 0) {
        float v1 = Pl[t], v2 = Pl[t + 256];
        float pp = v1 * v1 - 2.0f * bias[t] * v1 + v2 * v2 - 2.0f * bias[t + 256] * v2;
#pragma unroll
        for (int off = 32; off; off >>= 1) pp += __shfl_xor(pp, off);
        if ((t & 63) == 0) red[t >> 6] = pp;
    }
    __syncthreads();

    if (jh == 0) {
        const float gt = sG[0][kl] + sG[1][kl];
        const int n = 512 + c;
        const int ck = k >> 5, s = (k >> 3) & 3, e = k & 7;
        Bsw[(size_t)ck * 18432 + n * 32 + ((s ^ (c & 3)) * 8) + e] = (bf16_t)gt;
    }
    if (kc == 0 && t == 0) ph[c] = red[0] + red[1] + red[2] + red[3];
}

// ---------------------------------------------------------------- K_MAIN
// 256 blocks x 512 thr, 2 blocks/CU (LDS 39.7 KB, VGPR<=128 via bounds).
// BK=32 -> 16 fine chunks: per-barrier DMA drain is 36.9 KB (half of BK=64),
// interleaving better across the two resident blocks (m114 wave-overlap).
// One MFMA per tile per chunk (16x16x32 consumes the whole chunk K).
__global__ __launch_bounds__(512, 4) void k_main(
    const float* __restrict__ query, const bf16_t* __restrict__ Bsw,
    const float* __restrict__ bias, const float* __restrict__ ph,
    float* __restrict__ out)
{
    __shared__ bf16_t Bb[18432];   // 36,864 B
    __shared__ bf16_t Ab[1024];    //  2,048 B
    __shared__ float qln[4][32];
    __shared__ float phs[NWAY];

    const int t = threadIdx.x, bm = blockIdx.x;
    if (t < NWAY) phs[t] = ph[t];

    const int l = t & 63, w = t >> 6;
    const int wm = w & 1, wn = w >> 1;
    const int r15 = l & 15, quad = l >> 4;

    const int xt   = ((quad ^ (r15 & 3)) * 8);     // k-seg = quad, xor row&3
    const int aoff = (wm * 16 + r15) * 32 + xt;
    const int boff = (wn * 144 + r15) * 32;        // + tt*512 + xt

    // A staging: threads 0..127 (waves 0,1): row am, seg as
    const int am = t >> 2, as = t & 3;
    const float* aq = query + (size_t)(bm * 32 + (am & 31)) * D + as * 8;
    const int adst = (am & 31) * 32 + ((as ^ (am & 3)) * 8);

    f32x4 acc[9];
#pragma unroll
    for (int i = 0; i < 9; ++i) acc[i] = (f32x4){0.f, 0.f, 0.f, 0.f};

    f32x4 a0, a1;                          // A prefetch registers (waves 0,1)
    if (t < 128) { a0 = *(const f32x4*)(aq); a1 = *(const f32x4*)(aq + 4); }

    for (int ck = 0; ck < 16; ++ck) {
        if (ck) __syncthreads();           // WAR: prior MFMA reads done
        if (t < 128) {                     // store A(ck) from prefetched regs
            bf16x8_t hv = { (bf16_t)a0[0], (bf16_t)a0[1], (bf16_t)a0[2], (bf16_t)a0[3],
                            (bf16_t)a1[0], (bf16_t)a1[1], (bf16_t)a1[2], (bf16_t)a1[3] };
            *(bf16x8_t*)(Ab + adst) = hv;
        }
        {   // B chunk DMA: 36 insts of 1 KB (waves 0..3 issue 5, waves 4..7 issue 4)
            const bf16_t* src = Bsw + (size_t)ck * 18432;
#pragma unroll
            for (int i = 0; i < 4; ++i) {
                const int off = (w * 4 + i) * 512 + l * 8;
                ld16(src + off, Bb + off);
            }
            if (w < 4) {
                const int off = (32 + w) * 512 + l * 8;
                ld16(src + off, Bb + off);
            }
        }
        __syncthreads();                   // drain DMA + A stores
        if (t < 128 && ck < 15) {          // prefetch A(ck+1); MFMA covers latency
            a0 = *(const f32x4*)(aq + (ck + 1) * 32);
            a1 = *(const f32x4*)(aq + (ck + 1) * 32 + 4);
        }

        bf16x8_t fa = *(const bf16x8_t*)(Ab + aoff);
#pragma unroll
        for (int tt = 0; tt < 9; ++tt) {
            bf16x8_t fb = *(const bf16x8_t*)(Bb + boff + tt * 512 + xt);
            acc[tt] = __builtin_amdgcn_mfma_f32_16x16x32_bf16(fa, fb, acc[tt], 0, 0, 0);
        }
    }

    // ---- qn = sum over W-cols of (e + bias)^2 ; constant bound, masked ----
    float qp[4] = {0.f, 0.f, 0.f, 0.f};
#pragma unroll
    for (int tt = 0; tt < 9; ++tt) {
        const int colbase = wn * 144 + tt * 16;
        const float m = (colbase < 512) ? 1.f : 0.f;           // wave-uniform
        const int bi = colbase + r15;
        const float bv = bias[bi < 512 ? bi : 511];            // clamped, L2-hot
#pragma unroll
        for (int reg = 0; reg < 4; ++reg) {
            float v = acc[tt][reg] + bv;
            qp[reg] += m * v * v;
        }
    }
#pragma unroll
    for (int reg = 0; reg < 4; ++reg) {
        float s = qp[reg];
        s += __shfl_xor(s, 1); s += __shfl_xor(s, 2);
        s += __shfl_xor(s, 4); s += __shfl_xor(s, 8);
        if (r15 == 0) qln[wn][wm * 16 + quad * 4 + reg] = s;
    }
    __syncthreads();

    // ---- wn==3 waves write dists: qt + ph[c] - 2 * (q.G_c) ----
    if (wn == 3) {
#pragma unroll
        for (int reg = 0; reg < 4; ++reg) {
            const int row_local = quad * 4 + reg;
            const float qt = qln[0][wm * 16 + row_local] + qln[1][wm * 16 + row_local] +
                             qln[2][wm * 16 + row_local] + qln[3][wm * 16 + row_local];
            const int rowg = bm * 32 + wm * 16 + row_local;
#pragma unroll
            for (int tg = 0; tg < 4; ++tg) {
                const int c = tg * 16 + r15;
                out[(size_t)rowg * NWAY + c] = qt + phs[c] - 2.0f * acc[5 + tg][reg];
            }
        }
    }
}

// ---------------------------------------------------------------- launch
extern "C" void kernel_launch(void* const* d_in, const int* in_sizes, int n_in,
                              void* d_out, int out_size, void* d_ws, size_t ws_size,
                              hipStream_t stream)
{
    const float* support = (const float*)d_in[0];
    const float* query   = (const float*)d_in[1];
    const float* W       = (const float*)d_in[2];
    const float* bias    = (const float*)d_in[3];
    float* out = (float*)d_out;

    char* ws = (char*)d_ws;
    bf16_t* Bsw = (bf16_t*)ws;                     // 589,824 B
    float*  ph  = (float*)(ws + 589824);           //     256 B
    float*  Pg  = (float*)(ws + 589824 + 256);     // 131,072 B

    k_prep1<<<384, 256, 0, stream>>>(support, W, bias, Pg, Bsw);
    k_prep2<<<256, 256, 0, stream>>>(Pg, W, bias, Bsw, ph);
    k_main<<<256, 512, 0, stream>>>(query, Bsw, bias, ph, out);
}